// Round 3
// baseline (2936.866 us; speedup 1.0000x reference)
//
#include <hip/hip_runtime.h>
#include <hip/hip_bf16.h>

// Problem constants (B=4, L=1024, D=512, H=8, E=64, DIN=1024, N=16, K=4, R=32)
#define BB 4
#define LL 1024
#define DD 512
#define HH 8
#define EE 64
#define DIN 1024
#define NN 16
#define KK 4
#define RR 32
#define BL (BB*LL)   // 4096 rows

using bf16 = __hip_bfloat16;

__device__ __forceinline__ float ldf(const float* p) { return *p; }
__device__ __forceinline__ float ldf(const bf16* p) { return __bfloat162float(*p); }
__device__ __forceinline__ void stf(float* p, float v) { *p = v; }
__device__ __forceinline__ void stf(bf16* p, float v) { *p = __float2bfloat16(v); }

// ---------------------------------------------------------------------------
// Generic tiled GEMM: C(M,N) = A(M,K) @ B(K,N) [+ bias], f32 accumulate in
// registers. 32x32 tile, 256 threads, each thread 4 rows x 1 col.
// M,N,K multiples of 32. A: TA row-major lda. B: f32 weights row-major ldb.
// ---------------------------------------------------------------------------
template <typename TA, typename TC>
__global__ void gemm_k(const TA* __restrict__ A, int lda,
                       const float* __restrict__ B, int ldb,
                       const float* __restrict__ bias,
                       TC* __restrict__ C, int ldc,
                       int M, int N, int Kd)
{
    __shared__ float As[32][33];
    __shared__ float Bs[32][33];
    const int tid = threadIdx.x;
    const int tx = tid & 31;       // col in tile
    const int ty = tid >> 5;       // 0..7
    const int rowBase = blockIdx.y * 32;
    const int colBase = blockIdx.x * 32;
    float acc[4] = {0.f, 0.f, 0.f, 0.f};

    for (int k0 = 0; k0 < Kd; k0 += 32) {
#pragma unroll
        for (int i = 0; i < 4; ++i) {
            int r = ty + 8 * i;
            As[r][tx] = ldf(&A[(size_t)(rowBase + r) * lda + k0 + tx]);
            Bs[r][tx] = B[(size_t)(k0 + r) * ldb + colBase + tx];
        }
        __syncthreads();
#pragma unroll 8
        for (int kk = 0; kk < 32; ++kk) {
            float bv = Bs[kk][tx];
#pragma unroll
            for (int i = 0; i < 4; ++i) acc[i] += As[ty + 8 * i][kk] * bv;
        }
        __syncthreads();
    }
#pragma unroll
    for (int i = 0; i < 4; ++i) {
        int row = rowBase + ty + 8 * i;
        int col = colBase + tx;
        float r = acc[i] + (bias ? bias[col] : 0.f);
        stf(&C[(size_t)row * ldc + col], r);
    }
}

// ---------------------------------------------------------------------------
// Attention scores + softmax. One block (256 thr) per (b,h,l) query row.
// Writes f32 attn directly into d_out's attn region.
// ---------------------------------------------------------------------------
__global__ void attn_softmax_k(const bf16* __restrict__ q,
                               const bf16* __restrict__ k,
                               float* __restrict__ attn)
{
    const int bid = blockIdx.x;           // (b*H + h)*L + l
    const int l = bid & (LL - 1);
    const int h = (bid >> 10) & (HH - 1);
    const int b = bid >> 13;
    const int tid = threadIdx.x;
    __shared__ float qs[EE];
    __shared__ float sc[LL];
    __shared__ float red[256];

    if (tid < EE) qs[tid] = ldf(&q[((size_t)(b * LL + l)) * DD + h * EE + tid]);
    __syncthreads();

    for (int s = tid; s < LL; s += 256) {
        const bf16* kp = k + ((size_t)(b * LL + s)) * DD + h * EE;
        float dot = 0.f;
#pragma unroll
        for (int e = 0; e < EE; ++e) dot += qs[e] * ldf(&kp[e]);
        sc[s] = dot * 0.125f;   // E^-0.5
    }
    __syncthreads();

    float m = -1e30f;
    for (int s = tid; s < LL; s += 256) m = fmaxf(m, sc[s]);
    red[tid] = m; __syncthreads();
    for (int off = 128; off > 0; off >>= 1) {
        if (tid < off) red[tid] = fmaxf(red[tid], red[tid + off]);
        __syncthreads();
    }
    const float mx = red[0];
    __syncthreads();

    float sum = 0.f;
    for (int s = tid; s < LL; s += 256) {
        float e = __expf(sc[s] - mx);
        sc[s] = e; sum += e;
    }
    red[tid] = sum; __syncthreads();
    for (int off = 128; off > 0; off >>= 1) {
        if (tid < off) red[tid] += red[tid + off];
        __syncthreads();
    }
    const float inv = 1.f / red[0];

    float* ap = attn + (size_t)bid * LL;
    for (int s = tid; s < LL; s += 256) ap[s] = sc[s] * inv;
}

// ---------------------------------------------------------------------------
// o = attn @ v. One block (64 thr = E) per (b,h,l); reads f32 attn row.
// ---------------------------------------------------------------------------
__global__ void attn_av_k(const float* __restrict__ attn,
                          const bf16* __restrict__ v,
                          bf16* __restrict__ o)
{
    const int bid = blockIdx.x;
    const int l = bid & (LL - 1);
    const int h = (bid >> 10) & (HH - 1);
    const int b = bid >> 13;
    const int e = threadIdx.x;
    const float* ap = attn + (size_t)bid * LL;
    const bf16* vp = v + (size_t)b * LL * DD + h * EE + e;
    float acc = 0.f;
    for (int s = 0; s < LL; ++s)
        acc += ap[s] * ldf(&vp[(size_t)s * DD]);
    stf(&o[((size_t)(b * LL + l)) * DD + h * EE + e], acc);
}

// ---------------------------------------------------------------------------
// out = LayerNorm(a + r) * g + beta.  One block (256 thr) per row of 512.
// ---------------------------------------------------------------------------
template <typename TA, typename TR, typename TO>
__global__ void add_ln_k(const TA* __restrict__ a, const TR* __restrict__ r,
                         const float* __restrict__ g, const float* __restrict__ be,
                         TO* __restrict__ out)
{
    const int row = blockIdx.x;
    const int tid = threadIdx.x;
    __shared__ float red[256];
    const size_t base = (size_t)row * DD;
    float v0 = ldf(&a[base + tid]) + ldf(&r[base + tid]);
    float v1 = ldf(&a[base + 256 + tid]) + ldf(&r[base + 256 + tid]);
    red[tid] = v0 + v1;
    __syncthreads();
    for (int off = 128; off > 0; off >>= 1) {
        if (tid < off) red[tid] += red[tid + off];
        __syncthreads();
    }
    const float mu = red[0] * (1.f / 512.f);
    __syncthreads();
    float d0 = v0 - mu, d1 = v1 - mu;
    red[tid] = d0 * d0 + d1 * d1;
    __syncthreads();
    for (int off = 128; off > 0; off >>= 1) {
        if (tid < off) red[tid] += red[tid + off];
        __syncthreads();
    }
    const float rs = rsqrtf(red[0] * (1.f / 512.f) + 1e-5f);
    stf(&out[base + tid], d0 * rs * g[tid] + be[tid]);
    stf(&out[base + 256 + tid], d1 * rs * g[tid + 256] + be[tid + 256]);
}

// ---------------------------------------------------------------------------
// Depthwise causal conv (K=4) + bias + SiLU. One thread per (b,t,c).
// ---------------------------------------------------------------------------
__global__ void conv_silu_k(const bf16* __restrict__ xz,
                            const float* __restrict__ w,
                            const float* __restrict__ cb,
                            bf16* __restrict__ xc)
{
    const int idx = blockIdx.x * 256 + threadIdx.x;   // b*2^20 + t*2^10 + c
    const int c = idx & (DIN - 1);
    const int t = (idx >> 10) & (LL - 1);
    const int b = idx >> 20;
    float acc = cb[c];
    const bf16* xi = xz + (size_t)b * LL * (2 * DIN) + c;
#pragma unroll
    for (int j = 0; j < KK; ++j) {
        int tt = t - (KK - 1) + j;
        if (tt >= 0) acc += w[c * KK + j] * ldf(&xi[(size_t)tt * (2 * DIN)]);
    }
    stf(&xc[idx], acc / (1.f + __expf(-acc)));
}

// softplus in-place on bf16 (bias already added by GEMM)
__global__ void softplus_k(bf16* __restrict__ p)
{
    const int idx = blockIdx.x * 256 + threadIdx.x;
    float v = ldf(&p[idx]);
    stf(&p[idx], (v > 20.f) ? v : log1pf(__expf(v)));
}

// ---------------------------------------------------------------------------
// Mamba selective scan + gate. Block = 256 thr = 16 channels x 16 states.
// Grid = (DIN/16, B). h in registers; reduce over n via 16-lane shfl.
// Writes y into the (dead) xi half of xz rows: xz[row*2048 + d].
// ---------------------------------------------------------------------------
__global__ void mamba_scan_k(const bf16* __restrict__ dt,
                             const bf16* __restrict__ xc,
                             const float* __restrict__ dbl,
                             bf16* __restrict__ xzm,
                             const float* __restrict__ Alog,
                             const float* __restrict__ Dv)
{
    const int tid = threadIdx.x;
    const int n = tid & (NN - 1);
    const int dl = tid >> 4;               // 0..15
    const int d = blockIdx.x * 16 + dl;
    const int b = blockIdx.y;
    const float A = -__expf(Alog[d * NN + n]);
    const float Dp = Dv[d];
    const bf16* dt_b = dt + (size_t)b * LL * DIN + d;
    const bf16* xc_b = xc + (size_t)b * LL * DIN + d;
    const float* dbl_b = dbl + (size_t)b * LL * 64;
    bf16* xz_b = xzm + (size_t)b * LL * (2 * DIN);   // row stride 2*DIN
    float h = 0.f;
    for (int t = 0; t < LL; ++t) {
        float dtv = ldf(&dt_b[(size_t)t * DIN]);
        float xcv = ldf(&xc_b[(size_t)t * DIN]);
        float Bm = dbl_b[(size_t)t * 64 + RR + n];
        float Cm = dbl_b[(size_t)t * 64 + RR + NN + n];
        h = h * __expf(dtv * A) + dtv * xcv * Bm;
        float p = h * Cm;
        p += __shfl_xor(p, 1);
        p += __shfl_xor(p, 2);
        p += __shfl_xor(p, 4);
        p += __shfl_xor(p, 8);
        if (n == 0) {
            float zv = ldf(&xz_b[(size_t)t * (2 * DIN) + DIN + d]);  // z
            float yv = p + xcv * Dp;
            yv *= zv / (1.f + __expf(-zv));
            stf(&xz_b[(size_t)t * (2 * DIN) + d], yv);               // y -> xi half
        }
    }
}

// ---------------------------------------------------------------------------
extern "C" void kernel_launch(void* const* d_in, const int* in_sizes, int n_in,
                              void* d_out, int out_size, void* d_ws, size_t ws_size,
                              hipStream_t stream)
{
    const float* x    = (const float*)d_in[0];
    const float* Wq   = (const float*)d_in[1];
    const float* bq   = (const float*)d_in[2];
    const float* Wk   = (const float*)d_in[3];
    const float* bk   = (const float*)d_in[4];
    const float* Wv   = (const float*)d_in[5];
    const float* bv   = (const float*)d_in[6];
    const float* Wo   = (const float*)d_in[7];
    const float* bo   = (const float*)d_in[8];
    const float* g1   = (const float*)d_in[9];
    const float* b1   = (const float*)d_in[10];
    const float* g2   = (const float*)d_in[11];
    const float* b2   = (const float*)d_in[12];
    const float* Win  = (const float*)d_in[13];
    const float* cw   = (const float*)d_in[14];
    const float* cb   = (const float*)d_in[15];
    const float* Wx   = (const float*)d_in[16];
    const float* Wdt  = (const float*)d_in[17];
    const float* bdt  = (const float*)d_in[18];
    const float* Alog = (const float*)d_in[19];
    const float* Dv   = (const float*)d_in[20];
    const float* Wout = (const float*)d_in[21];

    float* out  = (float*)d_out;                     // (B,L,D) f32
    float* attn = out + (size_t)BL * DD;             // (B,H,L,L) f32

    // bf16 workspace arena, ~51.4 MB total.
    bf16* wsb = (bf16*)d_ws;
    bf16* q    = wsb + 0;          // 2,097,152 elems; later reused as newx
    bf16* k    = wsb + 2097152;    // 2,097,152; later reused as x1
    bf16* v    = wsb + 4194304;    // 2,097,152
    bf16* o    = wsb + 6291456;    // 2,097,152; later reused as ym
    bf16* xz   = wsb + 8388608;    // 8,388,608 (xi half later reused as y)
    bf16* xc   = wsb + 16777216;   // 4,194,304
    bf16* dtb  = wsb + 20971520;   // 4,194,304
    float* dbl = (float*)(wsb + 25165824);  // 262,144 f32
    bf16* newx = q;
    bf16* x1   = k;
    bf16* ym   = o;

    const dim3 blk(256);

    // QKV projections (f32 in, bf16 out)
    gemm_k<float, bf16><<<dim3(DD/32, BL/32), blk, 0, stream>>>(x, DD, Wq, DD, bq, q, DD, BL, DD, DD);
    gemm_k<float, bf16><<<dim3(DD/32, BL/32), blk, 0, stream>>>(x, DD, Wk, DD, bk, k, DD, BL, DD, DD);
    gemm_k<float, bf16><<<dim3(DD/32, BL/32), blk, 0, stream>>>(x, DD, Wv, DD, bv, v, DD, BL, DD, DD);

    // Attention (attn written f32 straight into d_out)
    attn_softmax_k<<<dim3(BB*HH*LL), blk, 0, stream>>>(q, k, attn);
    attn_av_k<<<dim3(BB*HH*LL), dim3(64), 0, stream>>>(attn, v, o);

    // Output projection + first residual LN (newx->q slot, x1->k slot)
    gemm_k<bf16, bf16><<<dim3(DD/32, BL/32), blk, 0, stream>>>(o, DD, Wo, DD, bo, newx, DD, BL, DD, DD);
    add_ln_k<float, bf16, bf16><<<dim3(BL), blk, 0, stream>>>(x, newx, g1, b1, x1);

    // Mamba: in-projection xz = x1 @ Win  (BL x 2048)
    gemm_k<bf16, bf16><<<dim3(2*DIN/32, BL/32), blk, 0, stream>>>(x1, DD, Win, 2*DIN, nullptr, xz, 2*DIN, BL, 2*DIN, DD);

    // Depthwise conv + SiLU
    conv_silu_k<<<dim3(BL*DIN/256), blk, 0, stream>>>(xz, cw, cb, xc);

    // dbl = xc @ Wx (N=64, f32 out)
    gemm_k<bf16, float><<<dim3(64/32, BL/32), blk, 0, stream>>>(xc, DIN, Wx, 64, nullptr, dbl, 64, BL, 64, DIN);

    // dt = softplus(dbl[:, :32] @ Wdt + bdt)
    gemm_k<float, bf16><<<dim3(DIN/32, BL/32), blk, 0, stream>>>(dbl, 64, Wdt, DIN, bdt, dtb, DIN, BL, DIN, RR);
    softplus_k<<<dim3(BL*DIN/256), blk, 0, stream>>>(dtb);

    // Selective scan + skip + gate (y written into xi half of xz)
    mamba_scan_k<<<dim3(DIN/16, BB), blk, 0, stream>>>(dtb, xc, dbl, xz, Alog, Dv);

    // Mamba out-projection: ym = y @ Wout (y rows have stride 2*DIN)
    gemm_k<bf16, bf16><<<dim3(DD/32, BL/32), blk, 0, stream>>>(xz, 2*DIN, Wout, DD, nullptr, ym, DD, BL, DD, DIN);

    // Final residual LN -> f32 out
    add_ln_k<bf16, bf16, float><<<dim3(BL), blk, 0, stream>>>(x1, ym, g2, b2, out);
}

// Round 4
// 1297.995 us; speedup vs baseline: 2.2626x; 2.2626x over previous
//
#include <hip/hip_runtime.h>
#include <hip/hip_bf16.h>

// Problem constants (B=4, L=1024, D=512, H=8, E=64, DIN=1024, N=16, K=4, R=32)
#define BB 4
#define LL 1024
#define DD 512
#define HH 8
#define EE 64
#define DIN 1024
#define NN 16
#define KK 4
#define RR 32
#define BL (BB*LL)   // 4096 rows

using bf16 = __hip_bfloat16;
typedef __attribute__((ext_vector_type(8))) short short8;   // 8 bf16 = 4 VGPRs
typedef __attribute__((ext_vector_type(4))) float f32x4;

__device__ __forceinline__ float ldf(const float* p) { return *p; }
__device__ __forceinline__ float ldf(const bf16* p) { return __bfloat162float(*p); }
__device__ __forceinline__ void stf(float* p, float v) { *p = v; }
__device__ __forceinline__ void stf(bf16* p, float v) { *p = __float2bfloat16(v); }
__device__ __forceinline__ short f2bs(float f) { bf16 h = __float2bfloat16(f); return *(short*)&h; }

// ---------------------------------------------------------------------------
// f32 -> bf16 elementwise convert
// ---------------------------------------------------------------------------
__global__ void cvt_k(const float* __restrict__ in, bf16* __restrict__ out, int n)
{
    int i = blockIdx.x * 256 + threadIdx.x;
    if (i < n) out[i] = __float2bfloat16(in[i]);
}

// ---------------------------------------------------------------------------
// Weight transpose: in f32 [Kd][Nd] row-major -> out bf16 [Nd][Kd] row-major.
// Tiled 32x32 via LDS, 256 threads. Kd,Nd multiples of 32.
// ---------------------------------------------------------------------------
__global__ void tpw_k(const float* __restrict__ in, bf16* __restrict__ outT,
                      int Kd, int Nd)
{
    __shared__ float t[32][33];
    const int n0 = blockIdx.x * 32, k0 = blockIdx.y * 32;
    const int tx = threadIdx.x & 31, ty = threadIdx.x >> 5;
#pragma unroll
    for (int i = 0; i < 4; ++i)
        t[ty + 8 * i][tx] = in[(size_t)(k0 + ty + 8 * i) * Nd + n0 + tx];
    __syncthreads();
#pragma unroll
    for (int i = 0; i < 4; ++i)
        outT[(size_t)(n0 + ty + 8 * i) * Kd + k0 + tx] = __float2bfloat16(t[tx][ty + 8 * i]);
}

// ---------------------------------------------------------------------------
// V transpose per head: vT[bh][e][l] = v[b][l][h*64+e]  (bf16 -> bf16)
// ---------------------------------------------------------------------------
__global__ void tpv_k(const bf16* __restrict__ v, bf16* __restrict__ vT)
{
    __shared__ float t[32][33];
    const int l0 = blockIdx.x * 32;
    const int e0 = blockIdx.y * 32;
    const int bh = blockIdx.z, b = bh >> 3, h = bh & 7;
    const int tx = threadIdx.x & 31, ty = threadIdx.x >> 5;
#pragma unroll
    for (int i = 0; i < 4; ++i)
        t[ty + 8 * i][tx] = ldf(&v[(size_t)(b * LL + l0 + ty + 8 * i) * DD + h * EE + e0 + tx]);
    __syncthreads();
#pragma unroll
    for (int i = 0; i < 4; ++i)
        stf(&vT[(size_t)(bh * EE + e0 + ty + 8 * i) * LL + l0 + tx], t[tx][ty + 8 * i]);
}

// ---------------------------------------------------------------------------
// MFMA GEMM: C[M][N] = A[M][K] @ Bt[N][K]^T (+bias). LDS-free: A and Bt are
// both row-major so both fragments are contiguous 16B loads.
// Block 256 = 4 waves in 2x2; wave tile 32x32 (2x2 MFMA tiles). Grid (N/64, M/64).
// ---------------------------------------------------------------------------
template <typename TC>
__global__ void mfma_gemm_k(const bf16* __restrict__ A, int lda,
                            const bf16* __restrict__ Bt, int ldb,
                            const float* __restrict__ bias,
                            TC* __restrict__ C, int ldc, int Kd)
{
    const int lane = threadIdx.x & 63;
    const int w = threadIdx.x >> 6;
    const int m = lane & 15, quad = lane >> 4;
    const int m0 = blockIdx.y * 64 + (w >> 1) * 32;
    const int n0 = blockIdx.x * 64 + (w & 1) * 32;
    f32x4 acc[2][2] = {};
    const bf16* a0p = A + (size_t)(m0 + m) * lda + quad * 8;
    const bf16* a1p = a0p + (size_t)16 * lda;
    const bf16* b0p = Bt + (size_t)(n0 + m) * ldb + quad * 8;
    const bf16* b1p = b0p + (size_t)16 * ldb;
    for (int k = 0; k < Kd; k += 32) {
        short8 a0 = *(const short8*)(a0p + k);
        short8 a1 = *(const short8*)(a1p + k);
        short8 b0 = *(const short8*)(b0p + k);
        short8 b1 = *(const short8*)(b1p + k);
        acc[0][0] = __builtin_amdgcn_mfma_f32_16x16x32_bf16(a0, b0, acc[0][0], 0, 0, 0);
        acc[0][1] = __builtin_amdgcn_mfma_f32_16x16x32_bf16(a0, b1, acc[0][1], 0, 0, 0);
        acc[1][0] = __builtin_amdgcn_mfma_f32_16x16x32_bf16(a1, b0, acc[1][0], 0, 0, 0);
        acc[1][1] = __builtin_amdgcn_mfma_f32_16x16x32_bf16(a1, b1, acc[1][1], 0, 0, 0);
    }
#pragma unroll
    for (int i = 0; i < 2; ++i)
#pragma unroll
        for (int j = 0; j < 2; ++j)
#pragma unroll
            for (int r = 0; r < 4; ++r) {
                int row = m0 + i * 16 + quad * 4 + r;
                int col = n0 + j * 16 + (lane & 15);
                float vv = acc[i][j][r] + (bias ? bias[col] : 0.f);
                stf(&C[(size_t)row * ldc + col], vv);
            }
}

// ---------------------------------------------------------------------------
// Fused scores + softmax. Block = 16 q-rows x full 1024 cols (4 waves x 256
// cols, 16 MFMA col-tiles per wave, acc stays in VGPRs). Writes f32 attn.
// Grid (L/16, B*H).
// ---------------------------------------------------------------------------
__global__ void scores_softmax_k(const bf16* __restrict__ q, const bf16* __restrict__ k,
                                 float* __restrict__ attn)
{
    const int rt = blockIdx.x;
    const int bh = blockIdx.y, b = bh >> 3, h = bh & 7;
    const int w = threadIdx.x >> 6;
    const int lane = threadIdx.x & 63;
    const int m = lane & 15, quad = lane >> 4;
    __shared__ float pm[4][16], ps[4][16];

    const bf16* qp = q + (size_t)(b * LL + rt * 16 + m) * DD + h * EE + quad * 8;
    short8 a0 = *(const short8*)(qp);
    short8 a1 = *(const short8*)(qp + 32);

    f32x4 acc[16];
#pragma unroll
    for (int t = 0; t < 16; ++t) {
        int srow = w * 256 + t * 16 + m;
        const bf16* kp = k + (size_t)(b * LL + srow) * DD + h * EE + quad * 8;
        short8 b0 = *(const short8*)(kp);
        short8 b1 = *(const short8*)(kp + 32);
        f32x4 c = {};
        c = __builtin_amdgcn_mfma_f32_16x16x32_bf16(a0, b0, c, 0, 0, 0);
        c = __builtin_amdgcn_mfma_f32_16x16x32_bf16(a1, b1, c, 0, 0, 0);
        acc[t] = c;
    }

#pragma unroll
    for (int r = 0; r < 4; ++r) {
        float mx = -1e30f;
#pragma unroll
        for (int t = 0; t < 16; ++t) { acc[t][r] *= 0.125f; mx = fmaxf(mx, acc[t][r]); }
        mx = fmaxf(mx, __shfl_xor(mx, 1)); mx = fmaxf(mx, __shfl_xor(mx, 2));
        mx = fmaxf(mx, __shfl_xor(mx, 4)); mx = fmaxf(mx, __shfl_xor(mx, 8));
        if (m == 0) pm[w][quad * 4 + r] = mx;
    }
    __syncthreads();
#pragma unroll
    for (int r = 0; r < 4; ++r) {
        float mx = fmaxf(fmaxf(pm[0][quad * 4 + r], pm[1][quad * 4 + r]),
                         fmaxf(pm[2][quad * 4 + r], pm[3][quad * 4 + r]));
        float s = 0.f;
#pragma unroll
        for (int t = 0; t < 16; ++t) { float e = __expf(acc[t][r] - mx); acc[t][r] = e; s += e; }
        s += __shfl_xor(s, 1); s += __shfl_xor(s, 2);
        s += __shfl_xor(s, 4); s += __shfl_xor(s, 8);
        if (m == 0) ps[w][quad * 4 + r] = s;
    }
    __syncthreads();
#pragma unroll
    for (int r = 0; r < 4; ++r) {
        float tot = ps[0][quad * 4 + r] + ps[1][quad * 4 + r] + ps[2][quad * 4 + r] + ps[3][quad * 4 + r];
        float inv = 1.f / tot;
        int row = rt * 16 + quad * 4 + r;
        float* op = attn + ((size_t)bh * LL + row) * LL + w * 256 + (lane & 15);
#pragma unroll
        for (int t = 0; t < 16; ++t) op[t * 16] = acc[t][r] * inv;
    }
}

// ---------------------------------------------------------------------------
// o = attn @ v via MFMA. A-frags repacked f32->bf16 on the fly from attn;
// B-frags contiguous from vT[bh][e][l]. Grid (L/16, B*H), 4 waves = 4 col tiles.
// ---------------------------------------------------------------------------
__global__ void attn_av_mfma_k(const float* __restrict__ attn, const bf16* __restrict__ vT,
                               bf16* __restrict__ o)
{
    const int rt = blockIdx.x;
    const int bh = blockIdx.y, b = bh >> 3, h = bh & 7;
    const int w = threadIdx.x >> 6;
    const int lane = threadIdx.x & 63;
    const int m = lane & 15, quad = lane >> 4;
    const float* pRow = attn + ((size_t)bh * LL + rt * 16 + m) * LL + quad * 8;
    const bf16* vp = vT + (size_t)(bh * EE + w * 16 + m) * LL + quad * 8;
    f32x4 acc = {};
    for (int k0 = 0; k0 < LL; k0 += 32) {
        f32x4 p0 = *(const f32x4*)(pRow + k0);
        f32x4 p1 = *(const f32x4*)(pRow + k0 + 4);
        short8 a;
        a[0] = f2bs(p0[0]); a[1] = f2bs(p0[1]); a[2] = f2bs(p0[2]); a[3] = f2bs(p0[3]);
        a[4] = f2bs(p1[0]); a[5] = f2bs(p1[1]); a[6] = f2bs(p1[2]); a[7] = f2bs(p1[3]);
        short8 bb = *(const short8*)(vp + k0);
        acc = __builtin_amdgcn_mfma_f32_16x16x32_bf16(a, bb, acc, 0, 0, 0);
    }
#pragma unroll
    for (int r = 0; r < 4; ++r) {
        int row = rt * 16 + quad * 4 + r;
        stf(&o[(size_t)(b * LL + row) * DD + h * EE + w * 16 + (lane & 15)], acc[r]);
    }
}

// ---------------------------------------------------------------------------
// VALU tiled GEMM (kept for the tiny Wdt GEMM with f32 A).
// ---------------------------------------------------------------------------
template <typename TA, typename TC>
__global__ void gemm_k(const TA* __restrict__ A, int lda,
                       const float* __restrict__ B, int ldb,
                       const float* __restrict__ bias,
                       TC* __restrict__ C, int ldc,
                       int M, int N, int Kd)
{
    __shared__ float As[32][33];
    __shared__ float Bs[32][33];
    const int tid = threadIdx.x;
    const int tx = tid & 31;
    const int ty = tid >> 5;
    const int rowBase = blockIdx.y * 32;
    const int colBase = blockIdx.x * 32;
    float acc[4] = {0.f, 0.f, 0.f, 0.f};

    for (int k0 = 0; k0 < Kd; k0 += 32) {
#pragma unroll
        for (int i = 0; i < 4; ++i) {
            int r = ty + 8 * i;
            As[r][tx] = ldf(&A[(size_t)(rowBase + r) * lda + k0 + tx]);
            Bs[r][tx] = B[(size_t)(k0 + r) * ldb + colBase + tx];
        }
        __syncthreads();
#pragma unroll 8
        for (int kk = 0; kk < 32; ++kk) {
            float bv = Bs[kk][tx];
#pragma unroll
            for (int i = 0; i < 4; ++i) acc[i] += As[ty + 8 * i][kk] * bv;
        }
        __syncthreads();
    }
#pragma unroll
    for (int i = 0; i < 4; ++i) {
        int row = rowBase + ty + 8 * i;
        int col = colBase + tx;
        float r = acc[i] + (bias ? bias[col] : 0.f);
        stf(&C[(size_t)row * ldc + col], r);
    }
}

// ---------------------------------------------------------------------------
// out = LayerNorm(a + r) * g + beta.  One block (256 thr) per row of 512.
// ---------------------------------------------------------------------------
template <typename TA, typename TR, typename TO>
__global__ void add_ln_k(const TA* __restrict__ a, const TR* __restrict__ r,
                         const float* __restrict__ g, const float* __restrict__ be,
                         TO* __restrict__ out)
{
    const int row = blockIdx.x;
    const int tid = threadIdx.x;
    __shared__ float red[256];
    const size_t base = (size_t)row * DD;
    float v0 = ldf(&a[base + tid]) + ldf(&r[base + tid]);
    float v1 = ldf(&a[base + 256 + tid]) + ldf(&r[base + 256 + tid]);
    red[tid] = v0 + v1;
    __syncthreads();
    for (int off = 128; off > 0; off >>= 1) {
        if (tid < off) red[tid] += red[tid + off];
        __syncthreads();
    }
    const float mu = red[0] * (1.f / 512.f);
    __syncthreads();
    float d0 = v0 - mu, d1 = v1 - mu;
    red[tid] = d0 * d0 + d1 * d1;
    __syncthreads();
    for (int off = 128; off > 0; off >>= 1) {
        if (tid < off) red[tid] += red[tid + off];
        __syncthreads();
    }
    const float rs = rsqrtf(red[0] * (1.f / 512.f) + 1e-5f);
    stf(&out[base + tid], d0 * rs * g[tid] + be[tid]);
    stf(&out[base + 256 + tid], d1 * rs * g[tid + 256] + be[tid + 256]);
}

// ---------------------------------------------------------------------------
// Depthwise causal conv (K=4) + bias + SiLU. One thread per (b,t,c).
// ---------------------------------------------------------------------------
__global__ void conv_silu_k(const bf16* __restrict__ xz,
                            const float* __restrict__ w,
                            const float* __restrict__ cb,
                            bf16* __restrict__ xc)
{
    const int idx = blockIdx.x * 256 + threadIdx.x;
    const int c = idx & (DIN - 1);
    const int t = (idx >> 10) & (LL - 1);
    const int b = idx >> 20;
    float acc = cb[c];
    const bf16* xi = xz + (size_t)b * LL * (2 * DIN) + c;
#pragma unroll
    for (int j = 0; j < KK; ++j) {
        int tt = t - (KK - 1) + j;
        if (tt >= 0) acc += w[c * KK + j] * ldf(&xi[(size_t)tt * (2 * DIN)]);
    }
    stf(&xc[idx], acc / (1.f + __expf(-acc)));
}

__global__ void softplus_k(bf16* __restrict__ p)
{
    const int idx = blockIdx.x * 256 + threadIdx.x;
    float v = ldf(&p[idx]);
    stf(&p[idx], (v > 20.f) ? v : log1pf(__expf(v)));
}

// ---------------------------------------------------------------------------
// Mamba selective scan + gate (unchanged). Writes y into xi half of xz.
// ---------------------------------------------------------------------------
__global__ void mamba_scan_k(const bf16* __restrict__ dt,
                             const bf16* __restrict__ xc,
                             const float* __restrict__ dbl,
                             bf16* __restrict__ xzm,
                             const float* __restrict__ Alog,
                             const float* __restrict__ Dv)
{
    const int tid = threadIdx.x;
    const int n = tid & (NN - 1);
    const int dl = tid >> 4;
    const int d = blockIdx.x * 16 + dl;
    const int b = blockIdx.y;
    const float A = -__expf(Alog[d * NN + n]);
    const float Dp = Dv[d];
    const bf16* dt_b = dt + (size_t)b * LL * DIN + d;
    const bf16* xc_b = xc + (size_t)b * LL * DIN + d;
    const float* dbl_b = dbl + (size_t)b * LL * 64;
    bf16* xz_b = xzm + (size_t)b * LL * (2 * DIN);
    float h = 0.f;
    for (int t = 0; t < LL; ++t) {
        float dtv = ldf(&dt_b[(size_t)t * DIN]);
        float xcv = ldf(&xc_b[(size_t)t * DIN]);
        float Bm = dbl_b[(size_t)t * 64 + RR + n];
        float Cm = dbl_b[(size_t)t * 64 + RR + NN + n];
        h = h * __expf(dtv * A) + dtv * xcv * Bm;
        float p = h * Cm;
        p += __shfl_xor(p, 1);
        p += __shfl_xor(p, 2);
        p += __shfl_xor(p, 4);
        p += __shfl_xor(p, 8);
        if (n == 0) {
            float zv = ldf(&xz_b[(size_t)t * (2 * DIN) + DIN + d]);
            float yv = p + xcv * Dp;
            yv *= zv / (1.f + __expf(-zv));
            stf(&xz_b[(size_t)t * (2 * DIN) + d], yv);
        }
    }
}

// ---------------------------------------------------------------------------
extern "C" void kernel_launch(void* const* d_in, const int* in_sizes, int n_in,
                              void* d_out, int out_size, void* d_ws, size_t ws_size,
                              hipStream_t stream)
{
    const float* x    = (const float*)d_in[0];
    const float* Wq   = (const float*)d_in[1];
    const float* bq   = (const float*)d_in[2];
    const float* Wk   = (const float*)d_in[3];
    const float* bk   = (const float*)d_in[4];
    const float* Wv   = (const float*)d_in[5];
    const float* bv   = (const float*)d_in[6];
    const float* Wo   = (const float*)d_in[7];
    const float* bo   = (const float*)d_in[8];
    const float* g1   = (const float*)d_in[9];
    const float* b1   = (const float*)d_in[10];
    const float* g2   = (const float*)d_in[11];
    const float* b2   = (const float*)d_in[12];
    const float* Win  = (const float*)d_in[13];
    const float* cw   = (const float*)d_in[14];
    const float* cb   = (const float*)d_in[15];
    const float* Wx   = (const float*)d_in[16];
    const float* Wdt  = (const float*)d_in[17];
    const float* bdt  = (const float*)d_in[18];
    const float* Alog = (const float*)d_in[19];
    const float* Dv   = (const float*)d_in[20];
    const float* Wout = (const float*)d_in[21];

    float* out  = (float*)d_out;                     // (B,L,D) f32
    float* attn = out + (size_t)BL * DD;             // (B,H,L,L) f32

    const size_t M1 = 1048576;
    bf16* wsb = (bf16*)d_ws;
    bf16* xb   = wsb;                 // 2M
    bf16* q    = wsb + 2*M1;          // 2M (reused as newx)
    bf16* kb   = wsb + 4*M1;          // 2M (reused as x1)
    bf16* v    = wsb + 6*M1;          // 2M (reused as ym)
    bf16* o    = wsb + 8*M1;          // 2M
    bf16* x1   = wsb + 10*M1;         // 2M
    bf16* xz   = wsb + 12*M1;         // 8M
    bf16* xc   = wsb + 20*M1;         // 4M
    bf16* dtb  = wsb + 24*M1;         // 4M
    float* dbl = (float*)(wsb + 28*M1);          // 262144 f32 (=512K bf16 slots)
    bf16* vT   = wsb + 28*M1 + 524288;           // 2M
    bf16* Wqt  = vT + 2*M1;
    bf16* Wkt  = Wqt + 262144;
    bf16* Wvt  = Wkt + 262144;
    bf16* Wot  = Wvt + 262144;
    bf16* Wint = Wot + 262144;        // 2048x512 = 1M
    bf16* Wxt  = Wint + M1;           // 64x1024
    bf16* Woutt= Wxt + 65536;         // 512x1024   (end ~69.3 MB)
    bf16* newx = q;
    bf16* ym   = v;

    const dim3 blk(256);

    // Stage 0: converts / transposes
    cvt_k<<<dim3(BL*DD/256), blk, 0, stream>>>(x, xb, BL*DD);
    tpw_k<<<dim3(DD/32, DD/32),  blk, 0, stream>>>(Wq,   Wqt,  DD, DD);
    tpw_k<<<dim3(DD/32, DD/32),  blk, 0, stream>>>(Wk,   Wkt,  DD, DD);
    tpw_k<<<dim3(DD/32, DD/32),  blk, 0, stream>>>(Wv,   Wvt,  DD, DD);
    tpw_k<<<dim3(DD/32, DD/32),  blk, 0, stream>>>(Wo,   Wot,  DD, DD);
    tpw_k<<<dim3(2*DIN/32, DD/32), blk, 0, stream>>>(Win, Wint, DD, 2*DIN);
    tpw_k<<<dim3(64/32, DIN/32), blk, 0, stream>>>(Wx,   Wxt,  DIN, 64);
    tpw_k<<<dim3(DD/32, DIN/32), blk, 0, stream>>>(Wout, Woutt, DIN, DD);

    // QKV projections (MFMA)
    mfma_gemm_k<bf16><<<dim3(DD/64, BL/64), blk, 0, stream>>>(xb, DD, Wqt, DD, bq, q,  DD, DD);
    mfma_gemm_k<bf16><<<dim3(DD/64, BL/64), blk, 0, stream>>>(xb, DD, Wkt, DD, bk, kb, DD, DD);
    mfma_gemm_k<bf16><<<dim3(DD/64, BL/64), blk, 0, stream>>>(xb, DD, Wvt, DD, bv, v,  DD, DD);
    tpv_k<<<dim3(LL/32, EE/32, BB*HH), blk, 0, stream>>>(v, vT);

    // Attention
    scores_softmax_k<<<dim3(LL/16, BB*HH), blk, 0, stream>>>(q, kb, attn);
    attn_av_mfma_k<<<dim3(LL/16, BB*HH), blk, 0, stream>>>(attn, vT, o);

    // Output projection + LN1
    mfma_gemm_k<bf16><<<dim3(DD/64, BL/64), blk, 0, stream>>>(o, DD, Wot, DD, bo, newx, DD, DD);
    add_ln_k<float, bf16, bf16><<<dim3(BL), blk, 0, stream>>>(x, newx, g1, b1, x1);

    // Mamba in-projection
    mfma_gemm_k<bf16><<<dim3(2*DIN/64, BL/64), blk, 0, stream>>>(x1, DD, Wint, DD, nullptr, xz, 2*DIN, DD);

    // Depthwise conv + SiLU
    conv_silu_k<<<dim3(BL*DIN/256), blk, 0, stream>>>(xz, cw, cb, xc);

    // dbl = xc @ Wx (f32 out)
    mfma_gemm_k<float><<<dim3(64/64, BL/64), blk, 0, stream>>>(xc, DIN, Wxt, DIN, nullptr, dbl, 64, DIN);

    // dt = softplus(dbl[:, :32] @ Wdt + bdt)  (VALU; f32 A)
    gemm_k<float, bf16><<<dim3(DIN/32, BL/32), blk, 0, stream>>>(dbl, 64, Wdt, DIN, bdt, dtb, DIN, BL, DIN, RR);
    softplus_k<<<dim3(BL*DIN/256), blk, 0, stream>>>(dtb);

    // Selective scan + skip + gate (y -> xi half of xz)
    mamba_scan_k<<<dim3(DIN/16, BB), blk, 0, stream>>>(dtb, xc, dbl, xz, Alog, Dv);

    // Mamba out-projection
    mfma_gemm_k<bf16><<<dim3(DD/64, BL/64), blk, 0, stream>>>(xz, 2*DIN, Woutt, DIN, nullptr, ym, DD, DIN);

    // Final residual LN -> f32 out
    add_ln_k<bf16, bf16, float><<<dim3(BL), blk, 0, stream>>>(x1, ym, g2, b2, out);
}

// Round 5
// 700.919 us; speedup vs baseline: 4.1900x; 1.8518x over previous
//
#include <hip/hip_runtime.h>
#include <hip/hip_bf16.h>

// Problem constants (B=4, L=1024, D=512, H=8, E=64, DIN=1024, N=16, K=4, R=32)
#define BB 4
#define LL 1024
#define DD 512
#define HH 8
#define EE 64
#define DIN 1024
#define NN 16
#define KK 4
#define RR 32
#define BL (BB*LL)   // 4096 rows
#define CC 16        // scan chunks
#define LC (LL/CC)   // 64 steps per chunk
#define BDN (BB*DIN*NN)   // 65536 independent recurrences

using bf16 = __hip_bfloat16;
typedef __attribute__((ext_vector_type(8))) short short8;   // 8 bf16 = 4 VGPRs
typedef __attribute__((ext_vector_type(4))) float f32x4;

__device__ __forceinline__ float ldf(const float* p) { return *p; }
__device__ __forceinline__ float ldf(const bf16* p) { return __bfloat162float(*p); }
__device__ __forceinline__ void stf(float* p, float v) { *p = v; }
__device__ __forceinline__ void stf(bf16* p, float v) { *p = __float2bfloat16(v); }
__device__ __forceinline__ short f2bs(float f) { bf16 h = __float2bfloat16(f); return *(short*)&h; }

// ---------------------------------------------------------------------------
// f32 -> bf16 elementwise convert
// ---------------------------------------------------------------------------
__global__ void cvt_k(const float* __restrict__ in, bf16* __restrict__ out, int n)
{
    int i = blockIdx.x * 256 + threadIdx.x;
    if (i < n) out[i] = __float2bfloat16(in[i]);
}

// ---------------------------------------------------------------------------
// Weight transpose: in f32 [Kd][Nd] row-major -> out bf16 [Nd][Kd] row-major.
// ---------------------------------------------------------------------------
__global__ void tpw_k(const float* __restrict__ in, bf16* __restrict__ outT,
                      int Kd, int Nd)
{
    __shared__ float t[32][33];
    const int n0 = blockIdx.x * 32, k0 = blockIdx.y * 32;
    const int tx = threadIdx.x & 31, ty = threadIdx.x >> 5;
#pragma unroll
    for (int i = 0; i < 4; ++i)
        t[ty + 8 * i][tx] = in[(size_t)(k0 + ty + 8 * i) * Nd + n0 + tx];
    __syncthreads();
#pragma unroll
    for (int i = 0; i < 4; ++i)
        outT[(size_t)(n0 + ty + 8 * i) * Kd + k0 + tx] = __float2bfloat16(t[tx][ty + 8 * i]);
}

// ---------------------------------------------------------------------------
// V transpose per head: vT[bh][e][l] = v[b][l][h*64+e]
// ---------------------------------------------------------------------------
__global__ void tpv_k(const bf16* __restrict__ v, bf16* __restrict__ vT)
{
    __shared__ float t[32][33];
    const int l0 = blockIdx.x * 32;
    const int e0 = blockIdx.y * 32;
    const int bh = blockIdx.z, b = bh >> 3, h = bh & 7;
    const int tx = threadIdx.x & 31, ty = threadIdx.x >> 5;
#pragma unroll
    for (int i = 0; i < 4; ++i)
        t[ty + 8 * i][tx] = ldf(&v[(size_t)(b * LL + l0 + ty + 8 * i) * DD + h * EE + e0 + tx]);
    __syncthreads();
#pragma unroll
    for (int i = 0; i < 4; ++i)
        stf(&vT[(size_t)(bh * EE + e0 + ty + 8 * i) * LL + l0 + tx], t[tx][ty + 8 * i]);
}

// ---------------------------------------------------------------------------
// MFMA GEMM: C[M][N] = A[M][K] @ Bt[N][K]^T (+bias). LDS-free.
// Block 256 = 4 waves 2x2; wave tile 32x32. Grid (N/64, M/64).
// ---------------------------------------------------------------------------
template <typename TC>
__global__ void mfma_gemm_k(const bf16* __restrict__ A, int lda,
                            const bf16* __restrict__ Bt, int ldb,
                            const float* __restrict__ bias,
                            TC* __restrict__ C, int ldc, int Kd)
{
    const int lane = threadIdx.x & 63;
    const int w = threadIdx.x >> 6;
    const int m = lane & 15, quad = lane >> 4;
    const int m0 = blockIdx.y * 64 + (w >> 1) * 32;
    const int n0 = blockIdx.x * 64 + (w & 1) * 32;
    f32x4 acc[2][2] = {};
    const bf16* a0p = A + (size_t)(m0 + m) * lda + quad * 8;
    const bf16* a1p = a0p + (size_t)16 * lda;
    const bf16* b0p = Bt + (size_t)(n0 + m) * ldb + quad * 8;
    const bf16* b1p = b0p + (size_t)16 * ldb;
    for (int k = 0; k < Kd; k += 32) {
        short8 a0 = *(const short8*)(a0p + k);
        short8 a1 = *(const short8*)(a1p + k);
        short8 b0 = *(const short8*)(b0p + k);
        short8 b1 = *(const short8*)(b1p + k);
        acc[0][0] = __builtin_amdgcn_mfma_f32_16x16x32_bf16(a0, b0, acc[0][0], 0, 0, 0);
        acc[0][1] = __builtin_amdgcn_mfma_f32_16x16x32_bf16(a0, b1, acc[0][1], 0, 0, 0);
        acc[1][0] = __builtin_amdgcn_mfma_f32_16x16x32_bf16(a1, b0, acc[1][0], 0, 0, 0);
        acc[1][1] = __builtin_amdgcn_mfma_f32_16x16x32_bf16(a1, b1, acc[1][1], 0, 0, 0);
    }
#pragma unroll
    for (int i = 0; i < 2; ++i)
#pragma unroll
        for (int j = 0; j < 2; ++j)
#pragma unroll
            for (int r = 0; r < 4; ++r) {
                int row = m0 + i * 16 + quad * 4 + r;
                int col = n0 + j * 16 + (lane & 15);
                float vv = acc[i][j][r] + (bias ? bias[col] : 0.f);
                stf(&C[(size_t)row * ldc + col], vv);
            }
}

// ---------------------------------------------------------------------------
// Fused scores + softmax (acc in VGPRs). Grid (L/16, B*H). Writes f32 attn.
// ---------------------------------------------------------------------------
__global__ void scores_softmax_k(const bf16* __restrict__ q, const bf16* __restrict__ k,
                                 float* __restrict__ attn)
{
    const int rt = blockIdx.x;
    const int bh = blockIdx.y, b = bh >> 3, h = bh & 7;
    const int w = threadIdx.x >> 6;
    const int lane = threadIdx.x & 63;
    const int m = lane & 15, quad = lane >> 4;
    __shared__ float pm[4][16], ps[4][16];

    const bf16* qp = q + (size_t)(b * LL + rt * 16 + m) * DD + h * EE + quad * 8;
    short8 a0 = *(const short8*)(qp);
    short8 a1 = *(const short8*)(qp + 32);

    f32x4 acc[16];
#pragma unroll
    for (int t = 0; t < 16; ++t) {
        int srow = w * 256 + t * 16 + m;
        const bf16* kp = k + (size_t)(b * LL + srow) * DD + h * EE + quad * 8;
        short8 b0 = *(const short8*)(kp);
        short8 b1 = *(const short8*)(kp + 32);
        f32x4 c = {};
        c = __builtin_amdgcn_mfma_f32_16x16x32_bf16(a0, b0, c, 0, 0, 0);
        c = __builtin_amdgcn_mfma_f32_16x16x32_bf16(a1, b1, c, 0, 0, 0);
        acc[t] = c;
    }

#pragma unroll
    for (int r = 0; r < 4; ++r) {
        float mx = -1e30f;
#pragma unroll
        for (int t = 0; t < 16; ++t) { acc[t][r] *= 0.125f; mx = fmaxf(mx, acc[t][r]); }
        mx = fmaxf(mx, __shfl_xor(mx, 1)); mx = fmaxf(mx, __shfl_xor(mx, 2));
        mx = fmaxf(mx, __shfl_xor(mx, 4)); mx = fmaxf(mx, __shfl_xor(mx, 8));
        if (m == 0) pm[w][quad * 4 + r] = mx;
    }
    __syncthreads();
#pragma unroll
    for (int r = 0; r < 4; ++r) {
        float mx = fmaxf(fmaxf(pm[0][quad * 4 + r], pm[1][quad * 4 + r]),
                         fmaxf(pm[2][quad * 4 + r], pm[3][quad * 4 + r]));
        float s = 0.f;
#pragma unroll
        for (int t = 0; t < 16; ++t) { float e = __expf(acc[t][r] - mx); acc[t][r] = e; s += e; }
        s += __shfl_xor(s, 1); s += __shfl_xor(s, 2);
        s += __shfl_xor(s, 4); s += __shfl_xor(s, 8);
        if (m == 0) ps[w][quad * 4 + r] = s;
    }
    __syncthreads();
#pragma unroll
    for (int r = 0; r < 4; ++r) {
        float tot = ps[0][quad * 4 + r] + ps[1][quad * 4 + r] + ps[2][quad * 4 + r] + ps[3][quad * 4 + r];
        float inv = 1.f / tot;
        int row = rt * 16 + quad * 4 + r;
        float* op = attn + ((size_t)bh * LL + row) * LL + w * 256 + (lane & 15);
#pragma unroll
        for (int t = 0; t < 16; ++t) op[t * 16] = acc[t][r] * inv;
    }
}

// ---------------------------------------------------------------------------
// o = attn @ v via MFMA, A repacked f32->bf16 on the fly. Grid (L/16, B*H).
// ---------------------------------------------------------------------------
__global__ void attn_av_mfma_k(const float* __restrict__ attn, const bf16* __restrict__ vT,
                               bf16* __restrict__ o)
{
    const int rt = blockIdx.x;
    const int bh = blockIdx.y, b = bh >> 3, h = bh & 7;
    const int w = threadIdx.x >> 6;
    const int lane = threadIdx.x & 63;
    const int m = lane & 15, quad = lane >> 4;
    const float* pRow = attn + ((size_t)bh * LL + rt * 16 + m) * LL + quad * 8;
    const bf16* vp = vT + (size_t)(bh * EE + w * 16 + m) * LL + quad * 8;
    f32x4 acc = {};
    for (int k0 = 0; k0 < LL; k0 += 32) {
        f32x4 p0 = *(const f32x4*)(pRow + k0);
        f32x4 p1 = *(const f32x4*)(pRow + k0 + 4);
        short8 a;
        a[0] = f2bs(p0[0]); a[1] = f2bs(p0[1]); a[2] = f2bs(p0[2]); a[3] = f2bs(p0[3]);
        a[4] = f2bs(p1[0]); a[5] = f2bs(p1[1]); a[6] = f2bs(p1[2]); a[7] = f2bs(p1[3]);
        short8 bb = *(const short8*)(vp + k0);
        acc = __builtin_amdgcn_mfma_f32_16x16x32_bf16(a, bb, acc, 0, 0, 0);
    }
#pragma unroll
    for (int r = 0; r < 4; ++r) {
        int row = rt * 16 + quad * 4 + r;
        stf(&o[(size_t)(b * LL + row) * DD + h * EE + w * 16 + (lane & 15)], acc[r]);
    }
}

// ---------------------------------------------------------------------------
// VALU tiled GEMM (kept for the tiny Wdt GEMM with f32 A).
// ---------------------------------------------------------------------------
template <typename TA, typename TC>
__global__ void gemm_k(const TA* __restrict__ A, int lda,
                       const float* __restrict__ B, int ldb,
                       const float* __restrict__ bias,
                       TC* __restrict__ C, int ldc,
                       int M, int N, int Kd)
{
    __shared__ float As[32][33];
    __shared__ float Bs[32][33];
    const int tid = threadIdx.x;
    const int tx = tid & 31;
    const int ty = tid >> 5;
    const int rowBase = blockIdx.y * 32;
    const int colBase = blockIdx.x * 32;
    float acc[4] = {0.f, 0.f, 0.f, 0.f};

    for (int k0 = 0; k0 < Kd; k0 += 32) {
#pragma unroll
        for (int i = 0; i < 4; ++i) {
            int r = ty + 8 * i;
            As[r][tx] = ldf(&A[(size_t)(rowBase + r) * lda + k0 + tx]);
            Bs[r][tx] = B[(size_t)(k0 + r) * ldb + colBase + tx];
        }
        __syncthreads();
#pragma unroll 8
        for (int kk = 0; kk < 32; ++kk) {
            float bv = Bs[kk][tx];
#pragma unroll
            for (int i = 0; i < 4; ++i) acc[i] += As[ty + 8 * i][kk] * bv;
        }
        __syncthreads();
    }
#pragma unroll
    for (int i = 0; i < 4; ++i) {
        int row = rowBase + ty + 8 * i;
        int col = colBase + tx;
        float r = acc[i] + (bias ? bias[col] : 0.f);
        stf(&C[(size_t)row * ldc + col], r);
    }
}

// ---------------------------------------------------------------------------
// out = LayerNorm(a + r) * g + beta.  One block (256 thr) per row of 512.
// ---------------------------------------------------------------------------
template <typename TA, typename TR, typename TO>
__global__ void add_ln_k(const TA* __restrict__ a, const TR* __restrict__ r,
                         const float* __restrict__ g, const float* __restrict__ be,
                         TO* __restrict__ out)
{
    const int row = blockIdx.x;
    const int tid = threadIdx.x;
    __shared__ float red[256];
    const size_t base = (size_t)row * DD;
    float v0 = ldf(&a[base + tid]) + ldf(&r[base + tid]);
    float v1 = ldf(&a[base + 256 + tid]) + ldf(&r[base + 256 + tid]);
    red[tid] = v0 + v1;
    __syncthreads();
    for (int off = 128; off > 0; off >>= 1) {
        if (tid < off) red[tid] += red[tid + off];
        __syncthreads();
    }
    const float mu = red[0] * (1.f / 512.f);
    __syncthreads();
    float d0 = v0 - mu, d1 = v1 - mu;
    red[tid] = d0 * d0 + d1 * d1;
    __syncthreads();
    for (int off = 128; off > 0; off >>= 1) {
        if (tid < off) red[tid] += red[tid + off];
        __syncthreads();
    }
    const float rs = rsqrtf(red[0] * (1.f / 512.f) + 1e-5f);
    stf(&out[base + tid], d0 * rs * g[tid] + be[tid]);
    stf(&out[base + 256 + tid], d1 * rs * g[tid + 256] + be[tid + 256]);
}

// ---------------------------------------------------------------------------
// Depthwise causal conv (K=4) + bias + SiLU.
// ---------------------------------------------------------------------------
__global__ void conv_silu_k(const bf16* __restrict__ xz,
                            const float* __restrict__ w,
                            const float* __restrict__ cb,
                            bf16* __restrict__ xc)
{
    const int idx = blockIdx.x * 256 + threadIdx.x;
    const int c = idx & (DIN - 1);
    const int t = (idx >> 10) & (LL - 1);
    const int b = idx >> 20;
    float acc = cb[c];
    const bf16* xi = xz + (size_t)b * LL * (2 * DIN) + c;
#pragma unroll
    for (int j = 0; j < KK; ++j) {
        int tt = t - (KK - 1) + j;
        if (tt >= 0) acc += w[c * KK + j] * ldf(&xi[(size_t)tt * (2 * DIN)]);
    }
    stf(&xc[idx], acc / (1.f + __expf(-acc)));
}

__global__ void softplus_k(bf16* __restrict__ p)
{
    const int idx = blockIdx.x * 256 + threadIdx.x;
    float v = ldf(&p[idx]);
    stf(&p[idx], (v > 20.f) ? v : log1pf(__expf(v)));
}

// ---------------------------------------------------------------------------
// Chunked selective scan, phase 1: per (b,d,n,chunk) compute
//   P = prod dA  and  S = chunk-local state starting from h=0.
// Layout P/S: [c][bdn] for coalesced stores/loads. Block 256 = 16d x 16n,
// grid ((DIN/16)*CC, B).
// ---------------------------------------------------------------------------
__global__ void scan_p1_k(const bf16* __restrict__ dt, const bf16* __restrict__ xc,
                          const float* __restrict__ dbl, const float* __restrict__ Alog,
                          float* __restrict__ P, float* __restrict__ S)
{
    const int tid = threadIdx.x;
    const int n = tid & (NN - 1);
    const int dl = tid >> 4;
    const int c = blockIdx.x & (CC - 1);
    const int d = (blockIdx.x >> 4) * 16 + dl;
    const int b = blockIdx.y;
    const float A = -__expf(Alog[d * NN + n]);
    const int t0 = c * LC;
    const bf16* dt_b = dt + ((size_t)b * LL + t0) * DIN + d;
    const bf16* xc_b = xc + ((size_t)b * LL + t0) * DIN + d;
    const float* dbl_b = dbl + ((size_t)b * LL + t0) * 64;
    float Pv = 1.f, Sv = 0.f;
    for (int t = 0; t < LC; ++t) {
        float dtv = ldf(&dt_b[(size_t)t * DIN]);
        float xcv = ldf(&xc_b[(size_t)t * DIN]);
        float Bm = dbl_b[(size_t)t * 64 + RR + n];
        float dA = __expf(dtv * A);
        Sv = Sv * dA + dtv * xcv * Bm;
        Pv *= dA;
    }
    const size_t bdn = ((size_t)(b * DIN + d)) * NN + n;
    P[(size_t)c * BDN + bdn] = Pv;
    S[(size_t)c * BDN + bdn] = Sv;
}

// ---------------------------------------------------------------------------
// Phase 2: serial carry scan over the CC chunks. One thread per bdn.
// Hc[c][bdn] = state entering chunk c.
// ---------------------------------------------------------------------------
__global__ void scan_p2_k(const float* __restrict__ P, const float* __restrict__ S,
                          float* __restrict__ Hc)
{
    const size_t bdn = (size_t)blockIdx.x * 256 + threadIdx.x;
    float h = 0.f;
#pragma unroll
    for (int c = 0; c < CC; ++c) {
        Hc[(size_t)c * BDN + bdn] = h;
        h = S[(size_t)c * BDN + bdn] + P[(size_t)c * BDN + bdn] * h;
    }
}

// ---------------------------------------------------------------------------
// Phase 3: replay each chunk from its carry-in; y = sum_n h*C + xc*D, gated
// by silu(z); y written into the xi half of xz. Same grid as phase 1.
// ---------------------------------------------------------------------------
__global__ void scan_p3_k(const bf16* __restrict__ dt, const bf16* __restrict__ xc,
                          const float* __restrict__ dbl, const float* __restrict__ Alog,
                          const float* __restrict__ Dv, const float* __restrict__ Hc,
                          bf16* __restrict__ xzm)
{
    const int tid = threadIdx.x;
    const int n = tid & (NN - 1);
    const int dl = tid >> 4;
    const int c = blockIdx.x & (CC - 1);
    const int d = (blockIdx.x >> 4) * 16 + dl;
    const int b = blockIdx.y;
    const float A = -__expf(Alog[d * NN + n]);
    const float Dp = Dv[d];
    const int t0 = c * LC;
    const bf16* dt_b = dt + ((size_t)b * LL + t0) * DIN + d;
    const bf16* xc_b = xc + ((size_t)b * LL + t0) * DIN + d;
    const float* dbl_b = dbl + ((size_t)b * LL + t0) * 64;
    bf16* xz_b = xzm + ((size_t)b * LL + t0) * (2 * DIN);
    const size_t bdn = ((size_t)(b * DIN + d)) * NN + n;
    float h = Hc[(size_t)c * BDN + bdn];
    for (int t = 0; t < LC; ++t) {
        float dtv = ldf(&dt_b[(size_t)t * DIN]);
        float xcv = ldf(&xc_b[(size_t)t * DIN]);
        float Bm = dbl_b[(size_t)t * 64 + RR + n];
        float Cm = dbl_b[(size_t)t * 64 + RR + NN + n];
        h = h * __expf(dtv * A) + dtv * xcv * Bm;
        float p = h * Cm;
        p += __shfl_xor(p, 1);
        p += __shfl_xor(p, 2);
        p += __shfl_xor(p, 4);
        p += __shfl_xor(p, 8);
        if (n == 0) {
            float zv = ldf(&xz_b[(size_t)t * (2 * DIN) + DIN + d]);
            float yv = p + xcv * Dp;
            yv *= zv / (1.f + __expf(-zv));
            stf(&xz_b[(size_t)t * (2 * DIN) + d], yv);
        }
    }
}

// ---------------------------------------------------------------------------
extern "C" void kernel_launch(void* const* d_in, const int* in_sizes, int n_in,
                              void* d_out, int out_size, void* d_ws, size_t ws_size,
                              hipStream_t stream)
{
    const float* x    = (const float*)d_in[0];
    const float* Wq   = (const float*)d_in[1];
    const float* bq   = (const float*)d_in[2];
    const float* Wk   = (const float*)d_in[3];
    const float* bk   = (const float*)d_in[4];
    const float* Wv   = (const float*)d_in[5];
    const float* bv   = (const float*)d_in[6];
    const float* Wo   = (const float*)d_in[7];
    const float* bo   = (const float*)d_in[8];
    const float* g1   = (const float*)d_in[9];
    const float* b1   = (const float*)d_in[10];
    const float* g2   = (const float*)d_in[11];
    const float* b2   = (const float*)d_in[12];
    const float* Win  = (const float*)d_in[13];
    const float* cw   = (const float*)d_in[14];
    const float* cb   = (const float*)d_in[15];
    const float* Wx   = (const float*)d_in[16];
    const float* Wdt  = (const float*)d_in[17];
    const float* bdt  = (const float*)d_in[18];
    const float* Alog = (const float*)d_in[19];
    const float* Dv   = (const float*)d_in[20];
    const float* Wout = (const float*)d_in[21];

    float* out  = (float*)d_out;                     // (B,L,D) f32
    float* attn = out + (size_t)BL * DD;             // (B,H,L,L) f32

    const size_t M1 = 1048576;
    bf16* wsb = (bf16*)d_ws;
    bf16* xb   = wsb;                 // 2M bf16 (dead after QKV gemms -> P)
    bf16* q    = wsb + 2*M1;          // 2M (newx; dead after LN1 -> S)
    bf16* kb   = wsb + 4*M1;          // 2M (x1 lives here? no: x1 separate)
    bf16* v    = wsb + 6*M1;          // 2M (reused as ym)
    bf16* o    = wsb + 8*M1;          // 2M (dead after Wo gemm -> Hc)
    bf16* x1   = wsb + 10*M1;         // 2M
    bf16* xz   = wsb + 12*M1;         // 8M
    bf16* xc   = wsb + 20*M1;         // 4M
    bf16* dtb  = wsb + 24*M1;         // 4M
    float* dbl = (float*)(wsb + 28*M1);          // 262144 f32
    bf16* vT   = wsb + 28*M1 + 524288;           // 2M
    bf16* Wqt  = vT + 2*M1;
    bf16* Wkt  = Wqt + 262144;
    bf16* Wvt  = Wkt + 262144;
    bf16* Wot  = Wvt + 262144;
    bf16* Wint = Wot + 262144;        // 2048x512 = 1M
    bf16* Wxt  = Wint + M1;           // 64x1024
    bf16* Woutt= Wxt + 65536;         // 512x1024   (end ~69.3 MB)
    bf16* newx = q;
    bf16* ym   = v;
    // Scan scratch aliases dead slots (each needs 4MB = 2M bf16 slots):
    float* Pp = (float*)xb;
    float* Sp = (float*)q;
    float* Hc = (float*)o;

    const dim3 blk(256);

    // Stage 0: converts / transposes
    cvt_k<<<dim3(BL*DD/256), blk, 0, stream>>>(x, xb, BL*DD);
    tpw_k<<<dim3(DD/32, DD/32),  blk, 0, stream>>>(Wq,   Wqt,  DD, DD);
    tpw_k<<<dim3(DD/32, DD/32),  blk, 0, stream>>>(Wk,   Wkt,  DD, DD);
    tpw_k<<<dim3(DD/32, DD/32),  blk, 0, stream>>>(Wv,   Wvt,  DD, DD);
    tpw_k<<<dim3(DD/32, DD/32),  blk, 0, stream>>>(Wo,   Wot,  DD, DD);
    tpw_k<<<dim3(2*DIN/32, DD/32), blk, 0, stream>>>(Win, Wint, DD, 2*DIN);
    tpw_k<<<dim3(64/32, DIN/32), blk, 0, stream>>>(Wx,   Wxt,  DIN, 64);
    tpw_k<<<dim3(DD/32, DIN/32), blk, 0, stream>>>(Wout, Woutt, DIN, DD);

    // QKV projections (MFMA)
    mfma_gemm_k<bf16><<<dim3(DD/64, BL/64), blk, 0, stream>>>(xb, DD, Wqt, DD, bq, q,  DD, DD);
    mfma_gemm_k<bf16><<<dim3(DD/64, BL/64), blk, 0, stream>>>(xb, DD, Wkt, DD, bk, kb, DD, DD);
    mfma_gemm_k<bf16><<<dim3(DD/64, BL/64), blk, 0, stream>>>(xb, DD, Wvt, DD, bv, v,  DD, DD);
    tpv_k<<<dim3(LL/32, EE/32, BB*HH), blk, 0, stream>>>(v, vT);

    // Attention
    scores_softmax_k<<<dim3(LL/16, BB*HH), blk, 0, stream>>>(q, kb, attn);
    attn_av_mfma_k<<<dim3(LL/16, BB*HH), blk, 0, stream>>>(attn, vT, o);

    // Output projection + LN1 (x1 gets its own slot now)
    mfma_gemm_k<bf16><<<dim3(DD/64, BL/64), blk, 0, stream>>>(o, DD, Wot, DD, bo, newx, DD, DD);
    add_ln_k<float, bf16, bf16><<<dim3(BL), blk, 0, stream>>>(x, newx, g1, b1, x1);

    // Mamba in-projection
    mfma_gemm_k<bf16><<<dim3(2*DIN/64, BL/64), blk, 0, stream>>>(x1, DD, Wint, DD, nullptr, xz, 2*DIN, DD);

    // Depthwise conv + SiLU
    conv_silu_k<<<dim3(BL*DIN/256), blk, 0, stream>>>(xz, cw, cb, xc);

    // dbl = xc @ Wx (f32 out)
    mfma_gemm_k<float><<<dim3(64/64, BL/64), blk, 0, stream>>>(xc, DIN, Wxt, DIN, nullptr, dbl, 64, DIN);

    // dt = softplus(dbl[:, :32] @ Wdt + bdt)
    gemm_k<float, bf16><<<dim3(DIN/32, BL/32), blk, 0, stream>>>(dbl, 64, Wdt, DIN, bdt, dtb, DIN, BL, DIN, RR);
    softplus_k<<<dim3(BL*DIN/256), blk, 0, stream>>>(dtb);

    // Chunked selective scan (3 phases) + skip + gate (y -> xi half of xz)
    scan_p1_k<<<dim3((DIN/16)*CC, BB), blk, 0, stream>>>(dtb, xc, dbl, Alog, Pp, Sp);
    scan_p2_k<<<dim3(BDN/256), blk, 0, stream>>>(Pp, Sp, Hc);
    scan_p3_k<<<dim3((DIN/16)*CC, BB), blk, 0, stream>>>(dtb, xc, dbl, Alog, Dv, Hc, xz);

    // Mamba out-projection
    mfma_gemm_k<bf16><<<dim3(DD/64, BL/64), blk, 0, stream>>>(xz, 2*DIN, Woutt, DIN, nullptr, ym, DD, DIN);

    // Final residual LN -> f32 out
    add_ln_k<bf16, bf16, float><<<dim3(BL), blk, 0, stream>>>(x1, ym, g2, b2, out);
}